// Round 11
// baseline (7696.637 us; speedup 1.0000x reference)
//
#include <hip/hip_runtime.h>
#include <stdint.h>

#define SLEN 4096
#define CLEN 16
#define EDIM 256
#define HDIM 512
#define CHD  4
#define NLBL 64
#define KIN  260   /* EDIM + CHD */
#define G4H  2048  /* 4*HDIM */

typedef unsigned long long u64;

__device__ __forceinline__ float sigf(float x){ return 1.0f/(1.0f+__expf(-x)); }
/* fast tanh: 1 - 2/(e^(2x)+1); saturates correctly for |x| large */
__device__ __forceinline__ float ftanh(float x){
  float e = __expf(2.0f*x);
  return 1.0f - 2.0f/(e+1.0f);
}
/* broadcast lane i of own wave, VALU path (v_readlane), no LDS */
#define RLANE(x,i) __uint_as_float(__builtin_amdgcn_readlane(__float_as_uint(x),(i)))

/* sc0 ("coherent") ops: load bypasses L1, reads the XCD's shared L2;
   store writes through to L2. Used ONLY as an opportunistic fast path —
   correctness is guaranteed by the agent-scope slow path. */
__device__ __forceinline__ u64 l2_load_u64(const u64* p){
  u64 v;
  asm volatile("global_load_dwordx2 %0, %1, off sc0\n\ts_waitcnt vmcnt(0)"
               : "=v"(v) : "v"(p) : "memory");
  return v;
}
__device__ __forceinline__ void l2_store_u64(u64* p, u64 v){
  asm volatile("global_store_dwordx2 %0, %1, off sc0"
               :: "v"(p), "v"(v) : "memory");
}

/* ---------------- char-level LSTM: one thread per word ---------------- */
__global__ void k_char_lstm(const float* __restrict__ chars, const int* __restrict__ lens,
                            const float* __restrict__ Wih, const float* __restrict__ Whh,
                            const float* __restrict__ bih, const float* __restrict__ bhh,
                            float* __restrict__ h_char){
  int s = blockIdx.x*blockDim.x + threadIdx.x;
  if (s >= SLEN) return;
  float wih[16], bb[16], whh[16][4];
  #pragma unroll
  for(int r=0;r<16;r++){
    wih[r]=Wih[r]; bb[r]=bih[r]+bhh[r];
    #pragma unroll
    for(int k=0;k<4;k++) whh[r][k]=Whh[r*4+k];
  }
  float x[16];
  #pragma unroll
  for(int i=0;i<4;i++){
    float4 v = *(const float4*)&chars[s*CLEN + 4*i];
    x[4*i+0]=v.x; x[4*i+1]=v.y; x[4*i+2]=v.z; x[4*i+3]=v.w;
  }
  float h[4]={0,0,0,0}, c[4]={0,0,0,0};
  int len = lens[s];
  #pragma unroll 1
  for(int t=0;t<CLEN;t++){
    float g[16];
    #pragma unroll
    for(int r=0;r<16;r++){
      float a = fmaf(x[t], wih[r], bb[r]);
      #pragma unroll
      for(int k=0;k<4;k++) a = fmaf(h[k], whh[r][k], a);
      g[r]=a;
    }
    bool m = t < len;
    #pragma unroll
    for(int j=0;j<4;j++){
      float ig=sigf(g[j]), fg=sigf(g[4+j]), gg=ftanh(g[8+j]), og=sigf(g[12+j]);
      float cn = fg*c[j] + ig*gg;
      float hn = og*ftanh(cn);
      if(m){ c[j]=cn; h[j]=hn; }
    }
  }
  #pragma unroll
  for(int j=0;j<4;j++) h_char[s*CHD+j]=h[j];
}

/* ------------- gather emb rows + h_char into word_in[4096][260] ------------- */
__global__ void k_gather(const int* __restrict__ sent, const float* __restrict__ emb,
                         const float* __restrict__ h_char, float* __restrict__ win){
  int s = blockIdx.x; int l = threadIdx.x; /* 64 threads */
  int row = sent[s];
  float4 v = *(const float4*)&emb[(size_t)row*EDIM + 4*l];
  *(float4*)&win[(size_t)s*KIN + 4*l] = v;
  if (l < CHD) win[(size_t)s*KIN + EDIM + l] = h_char[s*CHD + l];
}

/* ------------- gx = word_in @ W_ih_w.T  (M=4096,N=2048,K=260) ------------- */
#define BK 20
__global__ __launch_bounds__(256) void k_gemm_gx(const float* __restrict__ win,
                          const float* __restrict__ Wihw, float* __restrict__ gx){
  __shared__ float As[BK][68];
  __shared__ float Bs[BK][68];
  int s0 = blockIdx.x*64, n0 = blockIdx.y*64;
  int tid = threadIdx.x;
  int tm = tid>>4, tn = tid&15;
  float acc[4][4] = {};
  for(int k0=0;k0<KIN;k0+=BK){
    __syncthreads();
    #pragma unroll
    for(int i=0;i<5;i++){
      int e = tid + i*256;
      int m = e/BK, kk = e - m*BK;
      As[kk][m] = win[(size_t)(s0+m)*KIN + k0+kk];
      Bs[kk][m] = Wihw[(size_t)(n0+m)*KIN + k0+kk];
    }
    __syncthreads();
    #pragma unroll
    for(int kk=0;kk<BK;kk++){
      float4 a4 = *(const float4*)&As[kk][tm*4];
      float4 b4 = *(const float4*)&Bs[kk][tn*4];
      float av[4]={a4.x,a4.y,a4.z,a4.w};
      float bv[4]={b4.x,b4.y,b4.z,b4.w};
      #pragma unroll
      for(int i=0;i<4;i++)
        #pragma unroll
        for(int j=0;j<4;j++)
          acc[i][j] = fmaf(av[i], bv[j], acc[i][j]);
    }
  }
  #pragma unroll
  for(int i=0;i<4;i++){
    float4 o; o.x=acc[i][0]; o.y=acc[i][1]; o.z=acc[i][2]; o.w=acc[i][3];
    *(float4*)&gx[(size_t)(s0+tm*4+i)*G4H + n0 + tn*4] = o;
  }
}

/* ------------- word-level LSTM: R8 skeleton + dual-path comm -------------
   Placement: 256 WGs; each reads HW_REG_XCC_ID, claims a roster slot on its
   XCD; the 32nd claimant of some XCD CASes the winner; losers exit. Whatever
   the outcome, correctness holds: comm has a FAST path (sc0 store/load,
   same-XCD L2) tried <=4 polls, then an agent-scope SLOW path (R1-R8-proven)
   polled unbounded. Producer publishes to BOTH (separate buffers).
   Everything else identical to R8 (register-broadcast dot, 1 barrier,
   ping-pong parity rows, exact-match tags, poison-immune). */
__global__ __launch_bounds__(512) void k_word_lstm(const float* __restrict__ gx,
    const float* __restrict__ Whh, const float* __restrict__ bih, const float* __restrict__ bhh,
    unsigned* __restrict__ ctrl, u64* __restrict__ comm_fast, u64* __restrict__ comm_slow,
    float* __restrict__ hs){
  __shared__ float pbuf[2][8][64];
  __shared__ int s_g;
  const int tid = threadIdx.x;
  /* ---- dynamic same-XCD placement claim ---- */
  if (tid==0){
    unsigned xcd;
    asm volatile("s_getreg_b32 %0, hwreg(HW_REG_XCC_ID)" : "=s"(xcd));
    xcd &= 7u;
    unsigned slot = __hip_atomic_fetch_add(&ctrl[xcd], 1u,
                        __ATOMIC_RELAXED, __HIP_MEMORY_SCOPE_AGENT);
    if (slot == 31u){
      unsigned exp = 0u;
      __hip_atomic_compare_exchange_strong(&ctrl[8], &exp, xcd+1u,
          __ATOMIC_RELAXED, __ATOMIC_RELAXED, __HIP_MEMORY_SCOPE_AGENT);
    }
    unsigned wn;
    do { wn = __hip_atomic_load(&ctrl[8], __ATOMIC_RELAXED, __HIP_MEMORY_SCOPE_AGENT); }
    while (wn == 0u);
    s_g = (slot < 32u && wn == xcd+1u) ? (int)slot : -1;
  }
  __syncthreads();
  const int g = s_g;
  if (g < 0) return;                 /* loser WG: exit */

  const int w   = tid>>6;            /* wave = k-chunk 0..7 */
  const int l   = tid&63;            /* gate row 0..63 */
  const int R   = (l>>4)*HDIM + g*16 + (l&15);
  const int gi  = g*16 + tid;        /* valid for tid<16 (writers) */
  /* resident weight slice: W_hh_w[R][w*64 .. +64) in 64 VGPRs */
  float4 w4[16];
  #pragma unroll
  for(int i=0;i<16;i++) w4[i] = *(const float4*)&Whh[(size_t)R*HDIM + w*64 + 4*i];
  float cst = 0.f;
  float bsum[4], gxv[4];
  if (tid<16){
    #pragma unroll
    for(int q=0;q<4;q++){
      bsum[q] = bih[q*HDIM + gi] + bhh[q*HDIM + gi];
      gxv[q]  = gx[(size_t)0*G4H + q*HDIM + gi];   /* t=0 prefetch */
    }
  }

  #pragma unroll 1
  for(int t=0;t<SLEN;t++){
    const int par = t&1;
    /* poll own slot: fast sc0/L2 path (<=4 tries), then proven agent path */
    float hv = 0.f;
    if (t>0){
      const u64* fs = &comm_fast[(size_t)par*HDIM + w*64 + l];
      u64 v = 0; bool got = false;
      #pragma unroll 1
      for(int p=0;p<4;p++){
        v = l2_load_u64(fs);
        if ((unsigned)(v>>32) == (unsigned)t){ got = true; break; }
      }
      if (!got){
        const u64* ss = &comm_slow[(size_t)par*HDIM + w*64 + l];
        do { v = __hip_atomic_load(ss, __ATOMIC_RELAXED, __HIP_MEMORY_SCOPE_AGENT); }
        while ((unsigned)(v>>32) != (unsigned)t);
      }
      union{unsigned u; float f;} cv; cv.u = (unsigned)v; hv = cv.f;
    }
    /* 64-MAC dot, h broadcast via v_readlane (4 acc chains) */
    float a0=0.f, a1=0.f, a2=0.f, a3=0.f;
    #pragma unroll
    for(int i=0;i<16;i++){
      float4 wv = w4[i];
      a0 = fmaf(wv.x, RLANE(hv,4*i+0), a0);
      a1 = fmaf(wv.y, RLANE(hv,4*i+1), a1);
      a2 = fmaf(wv.z, RLANE(hv,4*i+2), a2);
      a3 = fmaf(wv.w, RLANE(hv,4*i+3), a3);
    }
    pbuf[par][w][l] = (a0+a1)+(a2+a3);
    __syncthreads();                      /* the ONLY barrier per step */
    /* wave 0: sum 8 partials per row, gather gates, pointwise, dual store */
    if (tid < 64){
      const float* pb = &pbuf[par][0][0];
      float s = pb[tid];
      #pragma unroll
      for(int q=1;q<8;q++) s += pb[q*64 + tid];
      float a16 = __shfl_down(s,16);
      float a32 = __shfl_down(s,32);
      float a48 = __shfl_down(s,48);
      if (tid<16){
        float gi_ = s   + gxv[0] + bsum[0];
        float gf_ = a16 + gxv[1] + bsum[1];
        float gg_ = a32 + gxv[2] + bsum[2];
        float go_ = a48 + gxv[3] + bsum[3];
        float cn = sigf(gf_)*cst + sigf(gi_)*ftanh(gg_);
        float hn = sigf(go_)*ftanh(cn);
        cst = cn;
        union{float f; unsigned u;} hb; hb.f = hn;
        u64 pk = ((u64)(unsigned)(t+1)<<32) | (u64)hb.u;
        const size_t off = (size_t)((t+1)&1)*HDIM + gi;
        l2_store_u64(&comm_fast[off], pk);                 /* fast: L2 */
        __hip_atomic_store(&comm_slow[off], pk,            /* slow: proven */
                           __ATOMIC_RELAXED, __HIP_MEMORY_SCOPE_AGENT);
        hs[(size_t)t*HDIM + gi] = hn;     /* history for k_out; off critical path */
        if (t+1 < SLEN){                  /* gx prefetch, overlaps next poll wait */
          #pragma unroll
          for(int q=0;q<4;q++) gxv[q] = gx[(size_t)(t+1)*G4H + q*HDIM + gi];
        }
      }
    }
  }
}

/* ------------- logits + log_softmax ------------- */
__global__ __launch_bounds__(256) void k_out(const float* __restrict__ hs,
        const float* __restrict__ Wout, const float* __restrict__ bout,
        float* __restrict__ out){
  __shared__ float hsub[HDIM];
  __shared__ float lg[NLBL];
  int s = blockIdx.x, tid = threadIdx.x;
  hsub[tid]     = hs[(size_t)s*HDIM + tid];
  hsub[tid+256] = hs[(size_t)s*HDIM + tid + 256];
  __syncthreads();
  int l = tid>>2, q = tid&3;
  float a = 0.f;
  const float* wrp = &Wout[(size_t)l*HDIM + q*128];
  const float* hr = &hsub[q*128];
  #pragma unroll 8
  for(int i=0;i<128;i++) a = fmaf(hr[i], wrp[i], a);
  a += __shfl_xor(a,1);
  a += __shfl_xor(a,2);
  if (q==0) lg[l] = a + bout[l];
  __syncthreads();
  if (tid < NLBL){
    float x = lg[tid];
    float mx = x;
    #pragma unroll
    for(int m=32;m>=1;m>>=1) mx = fmaxf(mx, __shfl_xor(mx,m));
    float ex = __expf(x-mx);
    float sm = ex;
    #pragma unroll
    for(int m=32;m>=1;m>>=1) sm += __shfl_xor(sm,m);
    out[(size_t)s*NLBL + tid] = x - mx - __logf(sm);
  }
}

extern "C" void kernel_launch(void* const* d_in, const int* in_sizes, int n_in,
                              void* d_out, int out_size, void* d_ws, size_t ws_size,
                              hipStream_t stream){
  const int*   sent  = (const int*)d_in[0];
  const float* chars = (const float*)d_in[1];
  const int*   lens  = (const int*)d_in[2];
  const float* emb   = (const float*)d_in[3];
  const float* Wihc  = (const float*)d_in[4];
  const float* Whhc  = (const float*)d_in[5];
  const float* bihc  = (const float*)d_in[6];
  const float* bhhc  = (const float*)d_in[7];
  const float* Wihw  = (const float*)d_in[8];
  const float* Whhw  = (const float*)d_in[9];
  const float* bihw  = (const float*)d_in[10];
  const float* bhhw  = (const float*)d_in[11];
  const float* Wout  = (const float*)d_in[12];
  const float* bout  = (const float*)d_in[13];
  float* out = (float*)d_out;

  /* workspace (floats): ctrl 32 | h_char 16384 | word_in 4096*260 | gx 4096*2048 |
     hs 4096*512 | comm_fast 2*512 u64 | comm_slow 2*512 u64.
     comm tags are 1..4096 exact-match; 0xAA poison can never match. */
  unsigned* ctrl = (unsigned*)d_ws;
  float* h_char = (float*)d_ws + 32;
  float* win    = h_char + 16384;
  float* gx     = win + (size_t)SLEN*KIN;
  float* hs     = gx + (size_t)SLEN*G4H;
  u64*   comm_fast = (u64*)(hs + (size_t)SLEN*HDIM);
  u64*   comm_slow = comm_fast + 2*HDIM;

  hipMemsetAsync(ctrl, 0, 64, stream);
  k_char_lstm<<<SLEN/256, 256, 0, stream>>>(chars,lens,Wihc,Whhc,bihc,bhhc,h_char);
  k_gather<<<SLEN, 64, 0, stream>>>(sent,emb,h_char,win);
  k_gemm_gx<<<dim3(SLEN/64, G4H/64), 256, 0, stream>>>(win,Wihw,gx);
  k_word_lstm<<<256, 512, 0, stream>>>(gx,Whhw,bihw,bhhw,ctrl,comm_fast,comm_slow,hs);
  k_out<<<SLEN, 256, 0, stream>>>(hs,Wout,bout,out);
}

// Round 12
// 6046.123 us; speedup vs baseline: 1.2730x; 1.2730x over previous
//
#include <hip/hip_runtime.h>
#include <stdint.h>

#define SLEN 4096
#define CLEN 16
#define EDIM 256
#define HDIM 512
#define CHD  4
#define NLBL 64
#define KIN  260   /* EDIM + CHD */
#define G4H  2048  /* 4*HDIM */

typedef unsigned long long u64;

__device__ __forceinline__ float sigf(float x){ return 1.0f/(1.0f+__expf(-x)); }
/* fast tanh: 1 - 2/(e^(2x)+1); saturates correctly for |x| large */
__device__ __forceinline__ float ftanh(float x){
  float e = __expf(2.0f*x);
  return 1.0f - 2.0f/(e+1.0f);
}
/* broadcast lane i of own wave, VALU path (v_readlane), no LDS */
#define RLANE(x,i) __uint_as_float(__builtin_amdgcn_readlane(__float_as_uint(x),(i)))

/* ---------------- char-level LSTM: one thread per word ---------------- */
__global__ void k_char_lstm(const float* __restrict__ chars, const int* __restrict__ lens,
                            const float* __restrict__ Wih, const float* __restrict__ Whh,
                            const float* __restrict__ bih, const float* __restrict__ bhh,
                            float* __restrict__ h_char){
  int s = blockIdx.x*blockDim.x + threadIdx.x;
  if (s >= SLEN) return;
  float wih[16], bb[16], whh[16][4];
  #pragma unroll
  for(int r=0;r<16;r++){
    wih[r]=Wih[r]; bb[r]=bih[r]+bhh[r];
    #pragma unroll
    for(int k=0;k<4;k++) whh[r][k]=Whh[r*4+k];
  }
  float x[16];
  #pragma unroll
  for(int i=0;i<4;i++){
    float4 v = *(const float4*)&chars[s*CLEN + 4*i];
    x[4*i+0]=v.x; x[4*i+1]=v.y; x[4*i+2]=v.z; x[4*i+3]=v.w;
  }
  float h[4]={0,0,0,0}, c[4]={0,0,0,0};
  int len = lens[s];
  #pragma unroll 1
  for(int t=0;t<CLEN;t++){
    float g[16];
    #pragma unroll
    for(int r=0;r<16;r++){
      float a = fmaf(x[t], wih[r], bb[r]);
      #pragma unroll
      for(int k=0;k<4;k++) a = fmaf(h[k], whh[r][k], a);
      g[r]=a;
    }
    bool m = t < len;
    #pragma unroll
    for(int j=0;j<4;j++){
      float ig=sigf(g[j]), fg=sigf(g[4+j]), gg=ftanh(g[8+j]), og=sigf(g[12+j]);
      float cn = fg*c[j] + ig*gg;
      float hn = og*ftanh(cn);
      if(m){ c[j]=cn; h[j]=hn; }
    }
  }
  #pragma unroll
  for(int j=0;j<4;j++) h_char[s*CHD+j]=h[j];
}

/* ------------- gather emb rows + h_char into word_in[4096][260] ------------- */
__global__ void k_gather(const int* __restrict__ sent, const float* __restrict__ emb,
                         const float* __restrict__ h_char, float* __restrict__ win){
  int s = blockIdx.x; int l = threadIdx.x; /* 64 threads */
  int row = sent[s];
  float4 v = *(const float4*)&emb[(size_t)row*EDIM + 4*l];
  *(float4*)&win[(size_t)s*KIN + 4*l] = v;
  if (l < CHD) win[(size_t)s*KIN + EDIM + l] = h_char[s*CHD + l];
}

/* ------------- gx = word_in @ W_ih_w.T  (M=4096,N=2048,K=260) ------------- */
#define BK 20
__global__ __launch_bounds__(256) void k_gemm_gx(const float* __restrict__ win,
                          const float* __restrict__ Wihw, float* __restrict__ gx){
  __shared__ float As[BK][68];
  __shared__ float Bs[BK][68];
  int s0 = blockIdx.x*64, n0 = blockIdx.y*64;
  int tid = threadIdx.x;
  int tm = tid>>4, tn = tid&15;
  float acc[4][4] = {};
  for(int k0=0;k0<KIN;k0+=BK){
    __syncthreads();
    #pragma unroll
    for(int i=0;i<5;i++){
      int e = tid + i*256;
      int m = e/BK, kk = e - m*BK;
      As[kk][m] = win[(size_t)(s0+m)*KIN + k0+kk];
      Bs[kk][m] = Wihw[(size_t)(n0+m)*KIN + k0+kk];
    }
    __syncthreads();
    #pragma unroll
    for(int kk=0;kk<BK;kk++){
      float4 a4 = *(const float4*)&As[kk][tm*4];
      float4 b4 = *(const float4*)&Bs[kk][tn*4];
      float av[4]={a4.x,a4.y,a4.z,a4.w};
      float bv[4]={b4.x,b4.y,b4.z,b4.w};
      #pragma unroll
      for(int i=0;i<4;i++)
        #pragma unroll
        for(int j=0;j<4;j++)
          acc[i][j] = fmaf(av[i], bv[j], acc[i][j]);
    }
  }
  #pragma unroll
  for(int i=0;i<4;i++){
    float4 o; o.x=acc[i][0]; o.y=acc[i][1]; o.z=acc[i][2]; o.w=acc[i][3];
    *(float4*)&gx[(size_t)(s0+tm*4+i)*G4H + n0 + tn*4] = o;
  }
}

/* ------------- word-level LSTM: 32 persistent WGs (R8 structure, best=6077us)
   + s_sleep backoff in the poll retry path (THE single variable this round).
   Mechanism: 512 comm slots on 64 LLC lines; ~256 threads poll each line;
   the producer's store to a line queues behind the poll-read stream. Evidence:
   poll depth 1/2/3 -> 6705/7381/7836us (monotone in poll traffic). s_sleep 1
   (~64cy) between retries cuts line read pressure ~4x at <=64cy granularity
   cost. Everything else byte-identical to R8. */
__global__ __launch_bounds__(512) void k_word_lstm(const float* __restrict__ gx,
    const float* __restrict__ Whh, const float* __restrict__ bih, const float* __restrict__ bhh,
    u64* __restrict__ comm, float* __restrict__ hs){
  __shared__ float pbuf[2][8][64];
  const int tid = threadIdx.x;
  const int g   = blockIdx.x;
  const int w   = tid>>6;            /* wave = k-chunk 0..7 */
  const int l   = tid&63;            /* gate row 0..63 */
  const int R   = (l>>4)*HDIM + g*16 + (l&15);
  const int gi  = g*16 + tid;        /* valid for tid<16 (writers) */
  /* resident weight slice: W_hh_w[R][w*64 .. +64) in 64 VGPRs */
  float4 w4[16];
  #pragma unroll
  for(int i=0;i<16;i++) w4[i] = *(const float4*)&Whh[(size_t)R*HDIM + w*64 + 4*i];
  float cst = 0.f;
  float bsum[4], gxv[4];
  if (tid<16){
    #pragma unroll
    for(int q=0;q<4;q++){
      bsum[q] = bih[q*HDIM + gi] + bhh[q*HDIM + gi];
      gxv[q]  = gx[(size_t)0*G4H + q*HDIM + gi];   /* t=0 prefetch */
    }
  }

  #pragma unroll 1
  for(int t=0;t<SLEN;t++){
    const int par = t&1;
    /* poll own slot: 1-deep tag-match, ping-pong row; s_sleep between retries */
    float hv = 0.f;
    if (t>0){
      const u64* slot = &comm[(size_t)par*HDIM + w*64 + l];
      u64 v = __hip_atomic_load(slot, __ATOMIC_RELAXED, __HIP_MEMORY_SCOPE_AGENT);
      while ((unsigned)(v>>32) != (unsigned)t){
        asm volatile("s_sleep 1");
        v = __hip_atomic_load(slot, __ATOMIC_RELAXED, __HIP_MEMORY_SCOPE_AGENT);
      }
      union{unsigned u; float f;} cv; cv.u = (unsigned)v; hv = cv.f;
    }
    /* 64-MAC dot, h broadcast via v_readlane (4 acc chains) */
    float a0=0.f, a1=0.f, a2=0.f, a3=0.f;
    #pragma unroll
    for(int i=0;i<16;i++){
      float4 wv = w4[i];
      a0 = fmaf(wv.x, RLANE(hv,4*i+0), a0);
      a1 = fmaf(wv.y, RLANE(hv,4*i+1), a1);
      a2 = fmaf(wv.z, RLANE(hv,4*i+2), a2);
      a3 = fmaf(wv.w, RLANE(hv,4*i+3), a3);
    }
    pbuf[par][w][l] = (a0+a1)+(a2+a3);
    __syncthreads();                      /* the ONLY barrier per step */
    /* wave 0: sum 8 partials per row, gather gates, pointwise, 128B store */
    if (tid < 64){
      const float* pb = &pbuf[par][0][0];
      float s = pb[tid];
      #pragma unroll
      for(int q=1;q<8;q++) s += pb[q*64 + tid];
      float a16 = __shfl_down(s,16);
      float a32 = __shfl_down(s,32);
      float a48 = __shfl_down(s,48);
      if (tid<16){
        float gi_ = s   + gxv[0] + bsum[0];
        float gf_ = a16 + gxv[1] + bsum[1];
        float gg_ = a32 + gxv[2] + bsum[2];
        float go_ = a48 + gxv[3] + bsum[3];
        float cn = sigf(gf_)*cst + sigf(gi_)*ftanh(gg_);
        float hn = sigf(go_)*ftanh(cn);
        cst = cn;
        union{float f; unsigned u;} hb; hb.f = hn;
        u64 pk = ((u64)(unsigned)(t+1)<<32) | (u64)hb.u;
        __hip_atomic_store(&comm[(size_t)((t+1)&1)*HDIM + gi], pk,
                           __ATOMIC_RELAXED, __HIP_MEMORY_SCOPE_AGENT);
        hs[(size_t)t*HDIM + gi] = hn;     /* history for k_out; off critical path */
        if (t+1 < SLEN){                  /* gx prefetch, overlaps next poll wait */
          #pragma unroll
          for(int q=0;q<4;q++) gxv[q] = gx[(size_t)(t+1)*G4H + q*HDIM + gi];
        }
      }
    }
  }
}

/* ------------- logits + log_softmax ------------- */
__global__ __launch_bounds__(256) void k_out(const float* __restrict__ hs,
        const float* __restrict__ Wout, const float* __restrict__ bout,
        float* __restrict__ out){
  __shared__ float hsub[HDIM];
  __shared__ float lg[NLBL];
  int s = blockIdx.x, tid = threadIdx.x;
  hsub[tid]     = hs[(size_t)s*HDIM + tid];
  hsub[tid+256] = hs[(size_t)s*HDIM + tid + 256];
  __syncthreads();
  int l = tid>>2, q = tid&3;
  float a = 0.f;
  const float* wrp = &Wout[(size_t)l*HDIM + q*128];
  const float* hr = &hsub[q*128];
  #pragma unroll 8
  for(int i=0;i<128;i++) a = fmaf(hr[i], wrp[i], a);
  a += __shfl_xor(a,1);
  a += __shfl_xor(a,2);
  if (q==0) lg[l] = a + bout[l];
  __syncthreads();
  if (tid < NLBL){
    float x = lg[tid];
    float mx = x;
    #pragma unroll
    for(int m=32;m>=1;m>>=1) mx = fmaxf(mx, __shfl_xor(mx,m));
    float ex = __expf(x-mx);
    float sm = ex;
    #pragma unroll
    for(int m=32;m>=1;m>>=1) sm += __shfl_xor(sm,m);
    out[(size_t)s*NLBL + tid] = x - mx - __logf(sm);
  }
}

extern "C" void kernel_launch(void* const* d_in, const int* in_sizes, int n_in,
                              void* d_out, int out_size, void* d_ws, size_t ws_size,
                              hipStream_t stream){
  const int*   sent  = (const int*)d_in[0];
  const float* chars = (const float*)d_in[1];
  const int*   lens  = (const int*)d_in[2];
  const float* emb   = (const float*)d_in[3];
  const float* Wihc  = (const float*)d_in[4];
  const float* Whhc  = (const float*)d_in[5];
  const float* bihc  = (const float*)d_in[6];
  const float* bhhc  = (const float*)d_in[7];
  const float* Wihw  = (const float*)d_in[8];
  const float* Whhw  = (const float*)d_in[9];
  const float* bihw  = (const float*)d_in[10];
  const float* bhhw  = (const float*)d_in[11];
  const float* Wout  = (const float*)d_in[12];
  const float* bout  = (const float*)d_in[13];
  float* out = (float*)d_out;

  /* workspace (floats): h_char 16384 | word_in 4096*260 | gx 4096*2048 |
     hs 4096*512 | comm 2*512 u64 (ping-pong, LLC-resident).
     comm tags are 1..4096 exact-match; 0xAA poison can never match. */
  float* h_char = (float*)d_ws;
  float* win    = h_char + 16384;
  float* gx     = win + (size_t)SLEN*KIN;
  float* hs     = gx + (size_t)SLEN*G4H;
  u64*   comm   = (u64*)(hs + (size_t)SLEN*HDIM);

  k_char_lstm<<<SLEN/256, 256, 0, stream>>>(chars,lens,Wihc,Whhc,bihc,bhhc,h_char);
  k_gather<<<SLEN, 64, 0, stream>>>(sent,emb,h_char,win);
  k_gemm_gx<<<dim3(SLEN/64, G4H/64), 256, 0, stream>>>(win,Wihw,gx);
  k_word_lstm<<<HDIM/16, 512, 0, stream>>>(gx,Whhw,bihw,bhhw,comm,hs);
  k_out<<<SLEN, 256, 0, stream>>>(hs,Wout,bout,out);
}